// Round 1
// baseline (415.195 us; speedup 1.0000x reference)
//
#include <hip/hip_runtime.h>

// MaxPool2d: kernel 2x2, stride 2x2, VALID padding, NCHW fp32.
// x: (16, 96, 224, 224) -> y: (16, 96, 112, 112)
// Pure streaming (no reuse): each thread produces 4 output columns via
// 2x float4 loads from each of the two contributing input rows and one
// float4 store. All accesses 16B-aligned (row pitch 224 floats = 896 B).

#define N_  16
#define C_  96
#define H_  224
#define W_  224
#define OH_ 112
#define OW_ 112

__global__ __launch_bounds__(256) void maxpool2d_k(
    const float* __restrict__ x, float* __restrict__ y, int total_quads) {
    int t = blockIdx.x * blockDim.x + threadIdx.x;
    if (t >= total_quads) return;

    // quad index within an output row (OW_/4 = 28 quads per row)
    int q = t % 28;
    int r = t / 28;          // r = (n*C_ + c)*OH_ + oh, in [0, N_*C_*OH_)
    int oh = r % OH_;
    int nc = r / OH_;

    const float* row0 = x + ((size_t)nc * H_ + (size_t)(2 * oh)) * W_ + q * 8;
    const float* row1 = row0 + W_;

    float4 a0 = *(const float4*)(row0);
    float4 a1 = *(const float4*)(row0 + 4);
    float4 b0 = *(const float4*)(row1);
    float4 b1 = *(const float4*)(row1 + 4);

    float4 o;
    o.x = fmaxf(fmaxf(a0.x, a0.y), fmaxf(b0.x, b0.y));
    o.y = fmaxf(fmaxf(a0.z, a0.w), fmaxf(b0.z, b0.w));
    o.z = fmaxf(fmaxf(a1.x, a1.y), fmaxf(b1.x, b1.y));
    o.w = fmaxf(fmaxf(a1.z, a1.w), fmaxf(b1.z, b1.w));

    *(float4*)(y + (size_t)r * OW_ + q * 4) = o;
}

extern "C" void kernel_launch(void* const* d_in, const int* in_sizes, int n_in,
                              void* d_out, int out_size, void* d_ws, size_t ws_size,
                              hipStream_t stream) {
    const float* x = (const float*)d_in[0];
    float* y = (float*)d_out;

    const int total_quads = N_ * C_ * OH_ * (OW_ / 4);  // 4,816,896
    const int block = 256;
    const int grid = (total_quads + block - 1) / block; // 18,816 blocks

    maxpool2d_k<<<grid, block, 0, stream>>>(x, y, total_quads);
}

// Round 3
// 399.764 us; speedup vs baseline: 1.0386x; 1.0386x over previous
//
#include <hip/hip_runtime.h>

// MaxPool2d: kernel 2x2, stride 2x2, VALID padding, NCHW fp32.
// x: (16, 96, 224, 224) -> y: (16, 96, 112, 112)
// Streaming, zero reuse. Each thread produces 2 adjacent output columns:
//   - one dense fvec4 (dwordx4) load from input row 2*oh   (16 B/lane stride)
//   - one dense fvec4 load from input row 2*oh+1
//   - one dense fvec2 (dwordx2) store
// All loads/stores non-temporal (read-once / write-once, skip cache pollution).
// Native clang ext_vector types (not HIP_vector_type) so the nontemporal
// builtins accept the pointers.

typedef float fvec4 __attribute__((ext_vector_type(4)));
typedef float fvec2 __attribute__((ext_vector_type(2)));

#define N_  16
#define C_  96
#define H_  224
#define W_  224
#define OH_ 112
#define OW_ 112
#define PAIRS_PER_ROW (OW_ / 2)   // 56

__global__ __launch_bounds__(256) void maxpool2d_k(
    const float* __restrict__ x, float* __restrict__ y, int total_pairs) {
    int t = blockIdx.x * blockDim.x + threadIdx.x;
    if (t >= total_pairs) return;

    int p  = t % PAIRS_PER_ROW;        // pair index within output row
    int r  = t / PAIRS_PER_ROW;        // r = (n*C_ + c)*OH_ + oh
    int oh = r % OH_;
    int nc = r / OH_;

    const fvec4* row0 = (const fvec4*)(x + ((size_t)nc * H_ + (size_t)(2 * oh)) * W_) + p;
    const fvec4* row1 = row0 + (W_ / 4);

    fvec4 a = __builtin_nontemporal_load(row0);
    fvec4 b = __builtin_nontemporal_load(row1);

    fvec2 o;
    o.x = fmaxf(fmaxf(a.x, a.y), fmaxf(b.x, b.y));
    o.y = fmaxf(fmaxf(a.z, a.w), fmaxf(b.z, b.w));

    fvec2* dst = (fvec2*)(y + (size_t)r * OW_) + p;
    __builtin_nontemporal_store(o, dst);
}

extern "C" void kernel_launch(void* const* d_in, const int* in_sizes, int n_in,
                              void* d_out, int out_size, void* d_ws, size_t ws_size,
                              hipStream_t stream) {
    const float* x = (const float*)d_in[0];
    float* y = (float*)d_out;

    const int total_pairs = N_ * C_ * OH_ * PAIRS_PER_ROW;  // 9,633,792
    const int block = 256;
    const int grid = (total_pairs + block - 1) / block;      // 37,632 blocks

    maxpool2d_k<<<grid, block, 0, stream>>>(x, y, total_pairs);
}